// Round 1
// baseline (552.351 us; speedup 1.0000x reference)
//
#include <hip/hip_runtime.h>
#include <math.h>

#define N_NODES 65536
#define N_EDGES 655360
#define N_GRAPHS 512
#define NPERG 128
#define KTOP 32
#define NOUT 27
#define OUT0_SIZE (N_GRAPHS * NOUT)   // 13824

// ---------------- CSR build ----------------

__global__ void count_kernel(const int* __restrict__ col, int* __restrict__ cnt) {
    int e = blockIdx.x * 256 + threadIdx.x;
    if (e < N_EDGES) atomicAdd(&cnt[col[e]], 1);
}

__global__ void dinv_kernel(const int* __restrict__ cnt, float* __restrict__ dinv) {
    int i = blockIdx.x * 256 + threadIdx.x;
    if (i < N_NODES) dinv[i] = rsqrtf((float)cnt[i] + 1.0f);
}

__global__ void scan1_kernel(const int* __restrict__ cnt, int* __restrict__ ptr, int* __restrict__ bsum) {
    __shared__ int tmp[256];
    int t = threadIdx.x, i = blockIdx.x * 256 + t;
    int v = cnt[i];
    tmp[t] = v; __syncthreads();
    for (int o = 1; o < 256; o <<= 1) {
        int u = (t >= o) ? tmp[t - o] : 0;
        __syncthreads();
        tmp[t] += u;
        __syncthreads();
    }
    ptr[i] = tmp[t] - v;              // block-local exclusive
    if (t == 255) bsum[blockIdx.x] = tmp[t];
}

__global__ void scan2_kernel(int* __restrict__ bsum) {
    __shared__ int tmp[256];
    int t = threadIdx.x;
    int v = bsum[t];
    tmp[t] = v; __syncthreads();
    for (int o = 1; o < 256; o <<= 1) {
        int u = (t >= o) ? tmp[t - o] : 0;
        __syncthreads();
        tmp[t] += u;
        __syncthreads();
    }
    bsum[t] = tmp[t] - v;             // exclusive block offsets
}

__global__ void scan3_kernel(int* __restrict__ ptr, const int* __restrict__ bsum) {
    int i = blockIdx.x * 256 + threadIdx.x;
    ptr[i] += bsum[blockIdx.x];
    if (i == 0) ptr[N_NODES] = N_EDGES;
}

__global__ void fill_kernel(const int* __restrict__ row, const int* __restrict__ col,
                            const int* __restrict__ ptr, int* __restrict__ cur,
                            const float* __restrict__ dinv,
                            int* __restrict__ csrc, float* __restrict__ ccoef) {
    int e = blockIdx.x * 256 + threadIdx.x;
    if (e >= N_EDGES) return;
    int r = row[e], d = col[e];
    int p = ptr[d] + atomicAdd(&cur[d], 1);
    csrc[p] = r;
    ccoef[p] = dinv[r] * dinv[d];
}

// ---------------- GEMM: Y[N][F_OUT] = X[N][F_IN(pitch)] @ W[F_IN][F_OUT] ----------------

template<int F_IN, int F_OUT>
__global__ __launch_bounds__(256) void gemm_kernel(const float* __restrict__ X, int pitch,
                                                   const float* __restrict__ W,
                                                   float* __restrict__ Y) {
    constexpr int BM = 32;
    constexpr int BK = (F_IN > 64) ? 64 : F_IN;
    constexpr int NCH = F_IN / BK;
    constexpr int CPT = F_OUT / 32;   // cols per thread
    __shared__ float xs[BM][BK];
    __shared__ float wsh[BK][F_OUT];
    int tid = threadIdx.x;
    int tc = tid & 31, tr = tid >> 5;
    int row0 = blockIdx.x * BM;
    float acc[4][CPT];
#pragma unroll
    for (int i = 0; i < 4; i++)
#pragma unroll
        for (int j = 0; j < CPT; j++) acc[i][j] = 0.f;

    for (int ch = 0; ch < NCH; ++ch) {
        constexpr int XV = BM * BK / 4;
        for (int q = tid; q < XV; q += 256) {
            int r = q / (BK / 4), kv = q % (BK / 4);
            float4 v = *(const float4*)(X + (size_t)(row0 + r) * pitch + ch * BK + kv * 4);
            *(float4*)&xs[r][kv * 4] = v;
        }
        constexpr int WV = BK * F_OUT / 4;
        for (int q = tid; q < WV; q += 256) {
            int kk = q / (F_OUT / 4), cv = q % (F_OUT / 4);
            float4 v = *(const float4*)(W + (size_t)(ch * BK + kk) * F_OUT + cv * 4);
            *(float4*)&wsh[kk][cv * 4] = v;
        }
        __syncthreads();
#pragma unroll 4
        for (int k = 0; k < BK; k++) {
            float xv[4];
#pragma unroll
            for (int i = 0; i < 4; i++) xv[i] = xs[tr * 4 + i][k];
#pragma unroll
            for (int j = 0; j < CPT; j++) {
                float wv = wsh[k][tc * CPT + j];
#pragma unroll
                for (int i = 0; i < 4; i++) acc[i][j] += xv[i] * wv;
            }
        }
        __syncthreads();
    }
#pragma unroll
    for (int i = 0; i < 4; i++)
#pragma unroll
        for (int j = 0; j < CPT; j++)
            Y[(size_t)(row0 + tr * 4 + i) * F_OUT + tc * CPT + j] = acc[i][j];
}

// ---------------- Aggregation + self-loop + bias + tanh ----------------

template<int F>
__global__ __launch_bounds__(256) void agg_kernel(const float* __restrict__ xw,
                                                  const int* __restrict__ ptr,
                                                  const int* __restrict__ csrc,
                                                  const float* __restrict__ ccoef,
                                                  const float* __restrict__ dinv,
                                                  const float* __restrict__ bias,
                                                  float* __restrict__ h, int coloff) {
    int gid = blockIdx.x * 256 + threadIdx.x;
    int n = gid / F;
    int c = gid % F;
    int p0 = ptr[n], p1 = ptr[n + 1];
    float s = 0.f;
    for (int p = p0; p < p1; ++p) {
        int src = csrc[p];
        s += ccoef[p] * xw[(size_t)src * F + c];
    }
    float di = dinv[n];
    float v = s + di * di * xw[(size_t)n * F + c] + bias[c];
    h[(size_t)n * 256 + coloff + c] = tanhf(v);
}

// ---------------- Sort-pool + conv5 + maxpool + conv6 + dense (one block per graph) ----------------

__global__ __launch_bounds__(256) void final_kernel(const float* __restrict__ h,
                                                    const float* __restrict__ w5, const float* __restrict__ b5,
                                                    const float* __restrict__ w6, const float* __restrict__ b6,
                                                    const float* __restrict__ dw, const float* __restrict__ db,
                                                    float* __restrict__ out) {
    __shared__ float skey[128];
    __shared__ int   sidx[128];
    __shared__ float ph[32][257];    // pooled rows, +1 pad breaks stride-256 conflicts
    __shared__ float w5s[16][256];
    __shared__ float z5[16][33];
    __shared__ float ms[16][17];
    __shared__ float z6[384];
    int g = blockIdx.x, t = threadIdx.x;

    if (t < 128) { skey[t] = h[(size_t)(g * NPERG + t) * 256 + 255]; sidx[t] = t; }
    for (int q = t; q < 16 * 256; q += 256) w5s[q >> 8][q & 255] = w5[q];
    __syncthreads();

    // bitonic sort, 128 elems: key descending, ties by index ascending (== stable argsort(-key))
    for (int size = 2; size <= 128; size <<= 1) {
        for (int stride = size >> 1; stride > 0; stride >>= 1) {
            if (t < 64) {
                int i = ((t & ~(stride - 1)) << 1) | (t & (stride - 1));
                int j = i | stride;
                float ki = skey[i], kj = skey[j];
                int ii = sidx[i], ij = sidx[j];
                bool desc = ((i & size) == 0);
                bool ibef = (ki > kj) || (ki == kj && ii < ij);
                if (desc != ibef) { skey[i] = kj; skey[j] = ki; sidx[i] = ij; sidx[j] = ii; }
            }
            __syncthreads();
        }
    }

    // top-k indices output (as float32; harness reads whole out buffer as f32)
    if (t < KTOP) out[OUT0_SIZE + g * KTOP + t] = (float)(g * NPERG + sidx[t]);

    // gather pooled rows into LDS
    for (int r = 0; r < KTOP; r++) {
        int node = g * NPERG + sidx[r];
        ph[r][t] = h[(size_t)node * 256 + t];
    }
    __syncthreads();

    // conv5 (stride 256, kernel 256 => one pooled row per output position) + relu
    {
        int o = t >> 5, l = t & 31;
        float a0 = 0.f, a1 = 0.f;
#pragma unroll 4
        for (int j = 0; j < 256; j++) {
            float pv = ph[l][j];
            a0 += pv * w5s[o][j];
            a1 += pv * w5s[o + 8][j];
        }
        z5[o][l]     = fmaxf(a0 + b5[o], 0.f);
        z5[o + 8][l] = fmaxf(a1 + b5[o + 8], 0.f);
    }
    __syncthreads();

    // maxpool window 2 stride 2: [16][32] -> [16][16]
    {
        int o = t >> 4, p = t & 15;
        ms[o][p] = fmaxf(z5[o][2 * p], z5[o][2 * p + 1]);
    }
    __syncthreads();

    // conv6: [16][16] -> [32][12], kernel 5, relu
    for (int q = t; q < 384; q += 256) {
        int o2 = q / 12, tt = q % 12;
        float a = b6[o2];
        for (int o = 0; o < 16; o++) {
#pragma unroll
            for (int k = 0; k < 5; k++)
                a += w6[(o2 * 16 + o) * 5 + k] * ms[o][tt + k];
        }
        z6[q] = fmaxf(a, 0.f);
    }
    __syncthreads();

    // dense: 384 -> 27
    if (t < NOUT) {
        float a = db[t];
        for (int i = 0; i < 384; i++) a += z6[i] * dw[i * NOUT + t];
        out[g * NOUT + t] = a;
    }
}

// ---------------- launch ----------------

extern "C" void kernel_launch(void* const* d_in, const int* in_sizes, int n_in,
                              void* d_out, int out_size, void* d_ws, size_t ws_size,
                              hipStream_t stream) {
    const float* x    = (const float*)d_in[0];
    const int*   edge = (const int*)d_in[1];
    const int*   row  = edge;
    const int*   col  = edge + N_EDGES;
    const float* W1 = (const float*)d_in[3];  const float* b1 = (const float*)d_in[4];
    const float* W2 = (const float*)d_in[5];  const float* b2 = (const float*)d_in[6];
    const float* W3 = (const float*)d_in[7];  const float* b3 = (const float*)d_in[8];
    const float* W4 = (const float*)d_in[9];  const float* b4 = (const float*)d_in[10];
    const float* w5 = (const float*)d_in[11]; const float* b5 = (const float*)d_in[12];
    const float* w6 = (const float*)d_in[13]; const float* b6 = (const float*)d_in[14];
    const float* dw = (const float*)d_in[15]; const float* db = (const float*)d_in[16];
    float* out = (float*)d_out;

    char* wsb = (char*)d_ws;
    size_t off = 0;
    auto alloc = [&](size_t bytes) -> void* {
        void* p = wsb + off;
        off = (off + bytes + 255) & ~(size_t)255;
        return p;
    };
    float* dinv  = (float*)alloc((size_t)N_NODES * 4);
    int*   cnt   = (int*)  alloc((size_t)N_NODES * 4);
    int*   ptr   = (int*)  alloc((size_t)(N_NODES + 1) * 4);
    int*   bsum  = (int*)  alloc(256 * 4);
    int*   csrc  = (int*)  alloc((size_t)N_EDGES * 4);
    float* ccoef = (float*)alloc((size_t)N_EDGES * 4);
    float* xw    = (float*)alloc((size_t)N_NODES * 128 * 4);
    float* h     = (float*)alloc((size_t)N_NODES * 256 * 4);
    (void)ws_size; (void)in_sizes; (void)n_in; (void)out_size;

    hipMemsetAsync(cnt, 0, (size_t)N_NODES * 4, stream);
    count_kernel<<<N_EDGES / 256, 256, 0, stream>>>(col, cnt);
    dinv_kernel<<<N_NODES / 256, 256, 0, stream>>>(cnt, dinv);
    scan1_kernel<<<256, 256, 0, stream>>>(cnt, ptr, bsum);
    scan2_kernel<<<1, 256, 0, stream>>>(bsum);
    scan3_kernel<<<256, 256, 0, stream>>>(ptr, bsum);
    hipMemsetAsync(cnt, 0, (size_t)N_NODES * 4, stream);
    fill_kernel<<<N_EDGES / 256, 256, 0, stream>>>(row, col, ptr, cnt, dinv, csrc, ccoef);

    // layer 1: x[N][128] @ W1[128][128] -> h[:, 0:128]
    gemm_kernel<128, 128><<<N_NODES / 32, 256, 0, stream>>>(x, 128, W1, xw);
    agg_kernel<128><<<(N_NODES * 128) / 256, 256, 0, stream>>>(xw, ptr, csrc, ccoef, dinv, b1, h, 0);
    // layer 2: h[:,0:128] @ W2[128][64] -> h[:, 128:192]
    gemm_kernel<128, 64><<<N_NODES / 32, 256, 0, stream>>>(h + 0, 256, W2, xw);
    agg_kernel<64><<<(N_NODES * 64) / 256, 256, 0, stream>>>(xw, ptr, csrc, ccoef, dinv, b2, h, 128);
    // layer 3: h[:,128:192] @ W3[64][32] -> h[:, 192:224]
    gemm_kernel<64, 32><<<N_NODES / 32, 256, 0, stream>>>(h + 128, 256, W3, xw);
    agg_kernel<32><<<(N_NODES * 32) / 256, 256, 0, stream>>>(xw, ptr, csrc, ccoef, dinv, b3, h, 192);
    // layer 4: h[:,192:224] @ W4[32][32] -> h[:, 224:256]
    gemm_kernel<32, 32><<<N_NODES / 32, 256, 0, stream>>>(h + 192, 256, W4, xw);
    agg_kernel<32><<<(N_NODES * 32) / 256, 256, 0, stream>>>(xw, ptr, csrc, ccoef, dinv, b4, h, 224);

    final_kernel<<<N_GRAPHS, 256, 0, stream>>>(h, w5, b5, w6, b6, dw, db, out);
}

// Round 2
// 366.800 us; speedup vs baseline: 1.5059x; 1.5059x over previous
//
#include <hip/hip_runtime.h>
#include <math.h>

#define N_NODES 65536
#define N_EDGES 655360
#define N_GRAPHS 512
#define NPERG 128
#define KTOP 32
#define NOUT 27
#define OUT0_SIZE (N_GRAPHS * NOUT)   // 13824

typedef unsigned int uint32;
typedef unsigned short ushort16;

__device__ __forceinline__ float blo(uint32 u) { return __uint_as_float(u << 16); }
__device__ __forceinline__ float bhi(uint32 u) { return __uint_as_float(u & 0xffff0000u); }
__device__ __forceinline__ ushort16 f2b(float f) {
    uint32 u = __float_as_uint(f);
    u += 0x7fffu + ((u >> 16) & 1u);   // round-to-nearest-even
    return (ushort16)(u >> 16);
}

// ---------------- CSR build ----------------

__global__ void count_kernel(const int* __restrict__ col, int* __restrict__ cnt) {
    int e = blockIdx.x * 256 + threadIdx.x;
    if (e < N_EDGES) atomicAdd(&cnt[col[e]], 1);
}

__global__ void dinv_kernel(const int* __restrict__ cnt, float* __restrict__ dinv) {
    int i = blockIdx.x * 256 + threadIdx.x;
    if (i < N_NODES) dinv[i] = rsqrtf((float)cnt[i] + 1.0f);
}

__global__ void scan1_kernel(const int* __restrict__ cnt, int* __restrict__ ptr, int* __restrict__ bsum) {
    __shared__ int tmp[256];
    int t = threadIdx.x, i = blockIdx.x * 256 + t;
    int v = cnt[i];
    tmp[t] = v; __syncthreads();
    for (int o = 1; o < 256; o <<= 1) {
        int u = (t >= o) ? tmp[t - o] : 0;
        __syncthreads();
        tmp[t] += u;
        __syncthreads();
    }
    ptr[i] = tmp[t] - v;
    if (t == 255) bsum[blockIdx.x] = tmp[t];
}

__global__ void scan2_kernel(int* __restrict__ bsum) {
    __shared__ int tmp[256];
    int t = threadIdx.x;
    int v = bsum[t];
    tmp[t] = v; __syncthreads();
    for (int o = 1; o < 256; o <<= 1) {
        int u = (t >= o) ? tmp[t - o] : 0;
        __syncthreads();
        tmp[t] += u;
        __syncthreads();
    }
    bsum[t] = tmp[t] - v;
}

__global__ void scan3_kernel(int* __restrict__ ptr, const int* __restrict__ bsum) {
    int i = blockIdx.x * 256 + threadIdx.x;
    ptr[i] += bsum[blockIdx.x];
    if (i == 0) ptr[N_NODES] = N_EDGES;
}

__global__ void fill_kernel(const int* __restrict__ row, const int* __restrict__ col,
                            const int* __restrict__ ptr, int* __restrict__ cur,
                            const float* __restrict__ dinv,
                            int* __restrict__ csrc, float* __restrict__ ccoef) {
    int e = blockIdx.x * 256 + threadIdx.x;
    if (e >= N_EDGES) return;
    int r = row[e], d = col[e];
    int p = ptr[d] + atomicAdd(&cur[d], 1);
    csrc[p] = r;
    ccoef[p] = dinv[r] * dinv[d];
}

// ---------------- GEMM: Y[N][F_OUT](bf16) = X[N][F_IN(pitch)] @ W[F_IN][F_OUT] ----------------

template<int F_IN, int F_OUT>
__global__ __launch_bounds__(256) void gemm_kernel(const float* __restrict__ X, int pitch,
                                                   const float* __restrict__ W,
                                                   ushort16* __restrict__ Y) {
    constexpr int BM = 32;
    constexpr int BK = (F_IN > 64) ? 64 : F_IN;
    constexpr int NCH = F_IN / BK;
    constexpr int CPT = F_OUT / 32;   // cols per thread
    __shared__ float xs[BM][BK];
    __shared__ float wsh[BK][F_OUT];
    int tid = threadIdx.x;
    int tc = tid & 31, tr = tid >> 5;
    int row0 = blockIdx.x * BM;
    float acc[4][CPT];
#pragma unroll
    for (int i = 0; i < 4; i++)
#pragma unroll
        for (int j = 0; j < CPT; j++) acc[i][j] = 0.f;

    for (int ch = 0; ch < NCH; ++ch) {
        constexpr int XV = BM * BK / 4;
        for (int q = tid; q < XV; q += 256) {
            int r = q / (BK / 4), kv = q % (BK / 4);
            float4 v = *(const float4*)(X + (size_t)(row0 + r) * pitch + ch * BK + kv * 4);
            *(float4*)&xs[r][kv * 4] = v;
        }
        constexpr int WV = BK * F_OUT / 4;
        for (int q = tid; q < WV; q += 256) {
            int kk = q / (F_OUT / 4), cv = q % (F_OUT / 4);
            float4 v = *(const float4*)(W + (size_t)(ch * BK + kk) * F_OUT + cv * 4);
            *(float4*)&wsh[kk][cv * 4] = v;
        }
        __syncthreads();
#pragma unroll 4
        for (int k = 0; k < BK; k++) {
            float xv[4];
#pragma unroll
            for (int i = 0; i < 4; i++) xv[i] = xs[tr * 4 + i][k];
#pragma unroll
            for (int j = 0; j < CPT; j++) {
                float wv = wsh[k][tc * CPT + j];
#pragma unroll
                for (int i = 0; i < 4; i++) acc[i][j] += xv[i] * wv;
            }
        }
        __syncthreads();
    }
#pragma unroll
    for (int i = 0; i < 4; i++)
#pragma unroll
        for (int j = 0; j < CPT; j++)
            Y[(size_t)(row0 + tr * 4 + i) * F_OUT + tc * CPT + j] = f2b(acc[i][j]);
}

// ---------------- Aggregation + self-loop + bias + tanh ----------------
// xw is bf16; 2 channels per lane; 4 interleaved edge streams for MLP.

template<int F>
__global__ __launch_bounds__(256) void agg_kernel(const ushort16* __restrict__ xw,
                                                  const int* __restrict__ ptr,
                                                  const int* __restrict__ csrc,
                                                  const float* __restrict__ ccoef,
                                                  const float* __restrict__ dinv,
                                                  const float* __restrict__ bias,
                                                  float* __restrict__ h, int coloff) {
    constexpr int L = F / 2;               // lanes per node
    int gid = blockIdx.x * 256 + threadIdx.x;
    int n = gid / L;
    int c2 = gid % L;                      // channel-pair index
    int p0 = ptr[n], p1 = ptr[n + 1];
    float s0 = 0.f, s1 = 0.f, t0 = 0.f, t1 = 0.f;
    float u0 = 0.f, u1 = 0.f, v0 = 0.f, v1 = 0.f;
    int p = p0;
    for (; p + 3 < p1; p += 4) {
        int sA = csrc[p], sB = csrc[p + 1], sC = csrc[p + 2], sD = csrc[p + 3];
        float cA = ccoef[p], cB = ccoef[p + 1], cC = ccoef[p + 2], cD = ccoef[p + 3];
        uint32 a = *(const uint32*)(xw + (size_t)sA * F + 2 * c2);
        uint32 b = *(const uint32*)(xw + (size_t)sB * F + 2 * c2);
        uint32 c = *(const uint32*)(xw + (size_t)sC * F + 2 * c2);
        uint32 d = *(const uint32*)(xw + (size_t)sD * F + 2 * c2);
        s0 += cA * blo(a); s1 += cA * bhi(a);
        t0 += cB * blo(b); t1 += cB * bhi(b);
        u0 += cC * blo(c); u1 += cC * bhi(c);
        v0 += cD * blo(d); v1 += cD * bhi(d);
    }
    for (; p < p1; ++p) {
        int sA = csrc[p]; float cA = ccoef[p];
        uint32 a = *(const uint32*)(xw + (size_t)sA * F + 2 * c2);
        s0 += cA * blo(a); s1 += cA * bhi(a);
    }
    s0 += t0 + u0 + v0;
    s1 += t1 + u1 + v1;
    float di = dinv[n];
    uint32 a = *(const uint32*)(xw + (size_t)n * F + 2 * c2);
    float r0 = s0 + di * di * blo(a) + bias[2 * c2];
    float r1 = s1 + di * di * bhi(a) + bias[2 * c2 + 1];
    float2 res;
    res.x = tanhf(r0);
    res.y = tanhf(r1);
    *(float2*)(h + (size_t)n * 256 + coloff + 2 * c2) = res;
}

// ---------------- Sort-pool + conv5 + maxpool + conv6 + dense (one block per graph) ----------------

__global__ __launch_bounds__(256) void final_kernel(const float* __restrict__ h,
                                                    const float* __restrict__ w5, const float* __restrict__ b5,
                                                    const float* __restrict__ w6, const float* __restrict__ b6,
                                                    const float* __restrict__ dw, const float* __restrict__ db,
                                                    float* __restrict__ out) {
    __shared__ float skey[128];
    __shared__ int   sidx[128];
    __shared__ float ph[32][257];
    __shared__ float w5s[16][256];
    __shared__ float z5[16][33];
    __shared__ float ms[16][17];
    __shared__ float z6[384];
    int g = blockIdx.x, t = threadIdx.x;

    if (t < 128) { skey[t] = h[(size_t)(g * NPERG + t) * 256 + 255]; sidx[t] = t; }
    for (int q = t; q < 16 * 256; q += 256) w5s[q >> 8][q & 255] = w5[q];
    __syncthreads();

    for (int size = 2; size <= 128; size <<= 1) {
        for (int stride = size >> 1; stride > 0; stride >>= 1) {
            if (t < 64) {
                int i = ((t & ~(stride - 1)) << 1) | (t & (stride - 1));
                int j = i | stride;
                float ki = skey[i], kj = skey[j];
                int ii = sidx[i], ij = sidx[j];
                bool desc = ((i & size) == 0);
                bool ibef = (ki > kj) || (ki == kj && ii < ij);
                if (desc != ibef) { skey[i] = kj; skey[j] = ki; sidx[i] = ij; sidx[j] = ii; }
            }
            __syncthreads();
        }
    }

    if (t < KTOP) out[OUT0_SIZE + g * KTOP + t] = (float)(g * NPERG + sidx[t]);

    for (int r = 0; r < KTOP; r++) {
        int node = g * NPERG + sidx[r];
        ph[r][t] = h[(size_t)node * 256 + t];
    }
    __syncthreads();

    {
        int o = t >> 5, l = t & 31;
        float a0 = 0.f, a1 = 0.f;
#pragma unroll 4
        for (int j = 0; j < 256; j++) {
            float pv = ph[l][j];
            a0 += pv * w5s[o][j];
            a1 += pv * w5s[o + 8][j];
        }
        z5[o][l]     = fmaxf(a0 + b5[o], 0.f);
        z5[o + 8][l] = fmaxf(a1 + b5[o + 8], 0.f);
    }
    __syncthreads();

    {
        int o = t >> 4, p = t & 15;
        ms[o][p] = fmaxf(z5[o][2 * p], z5[o][2 * p + 1]);
    }
    __syncthreads();

    for (int q = t; q < 384; q += 256) {
        int o2 = q / 12, tt = q % 12;
        float a = b6[o2];
        for (int o = 0; o < 16; o++) {
#pragma unroll
            for (int k = 0; k < 5; k++)
                a += w6[(o2 * 16 + o) * 5 + k] * ms[o][tt + k];
        }
        z6[q] = fmaxf(a, 0.f);
    }
    __syncthreads();

    if (t < NOUT) {
        float a = db[t];
        for (int i = 0; i < 384; i++) a += z6[i] * dw[i * NOUT + t];
        out[g * NOUT + t] = a;
    }
}

// ---------------- launch ----------------

extern "C" void kernel_launch(void* const* d_in, const int* in_sizes, int n_in,
                              void* d_out, int out_size, void* d_ws, size_t ws_size,
                              hipStream_t stream) {
    const float* x    = (const float*)d_in[0];
    const int*   edge = (const int*)d_in[1];
    const int*   row  = edge;
    const int*   col  = edge + N_EDGES;
    const float* W1 = (const float*)d_in[3];  const float* b1 = (const float*)d_in[4];
    const float* W2 = (const float*)d_in[5];  const float* b2 = (const float*)d_in[6];
    const float* W3 = (const float*)d_in[7];  const float* b3 = (const float*)d_in[8];
    const float* W4 = (const float*)d_in[9];  const float* b4 = (const float*)d_in[10];
    const float* w5 = (const float*)d_in[11]; const float* b5 = (const float*)d_in[12];
    const float* w6 = (const float*)d_in[13]; const float* b6 = (const float*)d_in[14];
    const float* dw = (const float*)d_in[15]; const float* db = (const float*)d_in[16];
    float* out = (float*)d_out;

    char* wsb = (char*)d_ws;
    size_t off = 0;
    auto alloc = [&](size_t bytes) -> void* {
        void* p = wsb + off;
        off = (off + bytes + 255) & ~(size_t)255;
        return p;
    };
    float*    dinv  = (float*)alloc((size_t)N_NODES * 4);
    int*      cnt   = (int*)  alloc((size_t)N_NODES * 4);
    int*      ptr   = (int*)  alloc((size_t)(N_NODES + 1) * 4);
    int*      bsum  = (int*)  alloc(256 * 4);
    int*      csrc  = (int*)  alloc((size_t)N_EDGES * 4);
    float*    ccoef = (float*)alloc((size_t)N_EDGES * 4);
    ushort16* xw    = (ushort16*)alloc((size_t)N_NODES * 128 * 2);
    float*    h     = (float*)alloc((size_t)N_NODES * 256 * 4);
    (void)ws_size; (void)in_sizes; (void)n_in; (void)out_size;

    hipMemsetAsync(cnt, 0, (size_t)N_NODES * 4, stream);
    count_kernel<<<N_EDGES / 256, 256, 0, stream>>>(col, cnt);
    dinv_kernel<<<N_NODES / 256, 256, 0, stream>>>(cnt, dinv);
    scan1_kernel<<<256, 256, 0, stream>>>(cnt, ptr, bsum);
    scan2_kernel<<<1, 256, 0, stream>>>(bsum);
    scan3_kernel<<<256, 256, 0, stream>>>(ptr, bsum);
    hipMemsetAsync(cnt, 0, (size_t)N_NODES * 4, stream);
    fill_kernel<<<N_EDGES / 256, 256, 0, stream>>>(row, col, ptr, cnt, dinv, csrc, ccoef);

    // layer 1: x[N][128] @ W1[128][128] -> h[:, 0:128]
    gemm_kernel<128, 128><<<N_NODES / 32, 256, 0, stream>>>(x, 128, W1, xw);
    agg_kernel<128><<<(N_NODES * 64) / 256, 256, 0, stream>>>(xw, ptr, csrc, ccoef, dinv, b1, h, 0);
    // layer 2: h[:,0:128] @ W2[128][64] -> h[:, 128:192]
    gemm_kernel<128, 64><<<N_NODES / 32, 256, 0, stream>>>(h + 0, 256, W2, xw);
    agg_kernel<64><<<(N_NODES * 32) / 256, 256, 0, stream>>>(xw, ptr, csrc, ccoef, dinv, b2, h, 128);
    // layer 3: h[:,128:192] @ W3[64][32] -> h[:, 192:224]
    gemm_kernel<64, 32><<<N_NODES / 32, 256, 0, stream>>>(h + 128, 256, W3, xw);
    agg_kernel<32><<<(N_NODES * 16) / 256, 256, 0, stream>>>(xw, ptr, csrc, ccoef, dinv, b3, h, 192);
    // layer 4: h[:,192:224] @ W4[32][32] -> h[:, 224:256]
    gemm_kernel<32, 32><<<N_NODES / 32, 256, 0, stream>>>(h + 192, 256, W4, xw);
    agg_kernel<32><<<(N_NODES * 16) / 256, 256, 0, stream>>>(xw, ptr, csrc, ccoef, dinv, b4, h, 224);

    final_kernel<<<N_GRAPHS, 256, 0, stream>>>(h, w5, b5, w6, b6, dw, db, out);
}